// Round 4
// baseline (738.170 us; speedup 1.0000x reference)
//
#include <hip/hip_runtime.h>
#include <math.h>

#define DM 512
#define NH 8
#define BS 1024
#define HIST 199
#define TT 200

__device__ __forceinline__ float dot8(const float4& a0, const float4& a1,
                                      const float4& b0, const float4& b1) {
  float p = a0.x * b0.x;
  p = fmaf(a0.y, b0.y, p);
  p = fmaf(a0.z, b0.z, p);
  p = fmaf(a0.w, b0.w, p);
  p = fmaf(a1.x, b1.x, p);
  p = fmaf(a1.y, b1.y, p);
  p = fmaf(a1.z, b1.z, p);
  p = fmaf(a1.w, b1.w, p);
  return p;
}

__device__ __forceinline__ float wred64(float p) {
  p += __shfl_xor(p, 1);
  p += __shfl_xor(p, 2);
  p += __shfl_xor(p, 4);
  p += __shfl_xor(p, 8);
  p += __shfl_xor(p, 16);
  p += __shfl_xor(p, 32);
  return p;
}

// ---------------------------------------------------------------------------
// Kernel A1 v3: q[b,j] = current[b,:] . Wq[j,:] + bq[j]   (unchanged)
// ---------------------------------------------------------------------------
__global__ __launch_bounds__(256, 4) void qproj_kernel(
    const float* __restrict__ cur, const float* __restrict__ Wq,
    const float* __restrict__ bq, float* __restrict__ q) {
  const int lane = threadIdx.x & 63;
  const int wave = threadIdx.x >> 6;
  const int bg = blockIdx.x >> 2;
  const int jq = blockIdx.x & 3;
  const int j0 = jq * 128 + wave * 32;
  float4 ca[4], cb[4];
#pragma unroll
  for (int bb = 0; bb < 4; ++bb) {
    const float* cp = cur + (size_t)(bg * 4 + bb) * DM;
    ca[bb] = *(const float4*)(cp + 4 * lane);
    cb[bb] = *(const float4*)(cp + 256 + 4 * lane);
  }
  float keep[2] = {0.f, 0.f};
  for (int r = 0; r < 32; ++r) {
    const float* wp = Wq + (size_t)(j0 + r) * DM;
    const float4 wa = *(const float4*)(wp + 4 * lane);
    const float4 wb = *(const float4*)(wp + 256 + 4 * lane);
    float pp[4];
#pragma unroll
    for (int bb = 0; bb < 4; ++bb)
      pp[bb] = wred64(dot8(ca[bb], cb[bb], wa, wb));
#pragma unroll
    for (int bb = 0; bb < 4; ++bb)
      if (lane == ((bb & 1) * 32 + r)) keep[bb >> 1] = pp[bb];
  }
  const int r = lane & 31, bh = lane >> 5;
  const int j = j0 + r;
#pragma unroll
  for (int s = 0; s < 2; ++s) {
    const int b = bg * 4 + 2 * s + bh;
    q[(size_t)b * DM + j] = keep[s] + bq[j];
  }
}

// ---------------------------------------------------------------------------
// Kernel A2: qk1[b,h,e], qc1[b,h]   (unchanged)
// ---------------------------------------------------------------------------
__global__ __launch_bounds__(256, 4) void qk_kernel(
    const float* __restrict__ q, const float* __restrict__ Wk,
    const float* __restrict__ bk, float* __restrict__ qk1,
    float* __restrict__ qc1) {
  __shared__ float q8[8][64];
  const int tid = threadIdx.x;
  const int bg = blockIdx.x >> 3;
  const int h = blockIdx.x & 7;
  for (int i = tid; i < 512; i += 256) {
    const int bl = i >> 6, d = i & 63;
    q8[bl][d] = q[(size_t)(bg * 8 + bl) * DM + h * 64 + d];
  }
  __syncthreads();
  float acc0[8], acc1[8];
#pragma unroll
  for (int bl = 0; bl < 8; ++bl) {
    acc0[bl] = 0.f;
    acc1[bl] = 0.f;
  }
  const int e = tid;
  const float* wkb = Wk + (size_t)h * 64 * DM;
  for (int d4 = 0; d4 < 64; d4 += 4) {
    float w0[4], w1[4];
#pragma unroll
    for (int dd = 0; dd < 4; ++dd) {
      w0[dd] = wkb[(size_t)(d4 + dd) * DM + e];
      w1[dd] = wkb[(size_t)(d4 + dd) * DM + e + 256];
    }
#pragma unroll
    for (int bl = 0; bl < 8; ++bl) {
      const float4 qq = *(const float4*)&q8[bl][d4];
      acc0[bl] = fmaf(qq.x, w0[0], acc0[bl]);
      acc0[bl] = fmaf(qq.y, w0[1], acc0[bl]);
      acc0[bl] = fmaf(qq.z, w0[2], acc0[bl]);
      acc0[bl] = fmaf(qq.w, w0[3], acc0[bl]);
      acc1[bl] = fmaf(qq.x, w1[0], acc1[bl]);
      acc1[bl] = fmaf(qq.y, w1[1], acc1[bl]);
      acc1[bl] = fmaf(qq.z, w1[2], acc1[bl]);
      acc1[bl] = fmaf(qq.w, w1[3], acc1[bl]);
    }
  }
#pragma unroll
  for (int bl = 0; bl < 8; ++bl) {
    const size_t base = ((size_t)(bg * 8 + bl) * NH + h) * DM;
    qk1[base + e] = acc0[bl] * 0.125f;
    qk1[base + e + 256] = acc1[bl] * 0.125f;
  }
  if (tid < 8) {
    float s = 0.f;
    for (int d = 0; d < 64; ++d) s += q8[tid][d] * bk[h * 64 + d];
    qc1[(size_t)(bg * 8 + tid) * NH + h] = s * 0.125f;
  }
}

// ---------------------------------------------------------------------------
// Kernel B v7: HEAD-PER-WAVE. Wave w owns head w outright: streams all 200
// rows, per row dot8 -> wred64 (result lane-UNIFORM) -> one exp -> uniform
// ls += w -> cA/cB += w*row. No scatter, no broadcasts, no staged LDS
// reduction, no barriers in the main loop, wave-local epilogue. LDS is just
// an 800B mask broadcast table. Rows are read by 8 waves of the same block
// (same CU) -> 7/8 reads are L1/L2 hits, HBM traffic unchanged (~417MB).
// Unroll-2 with 2-row prefetch: two independent 6-deep shuffle chains in
// flight. Targets the ~85% stall (v4: VALUBusy 11.6%) by removing all
// cross-wave coupling.
// ---------------------------------------------------------------------------
__global__ __launch_bounds__(512, 8) void attn_kernel(
    const float* __restrict__ cur, const float* __restrict__ prev,
    const float* __restrict__ mask, const float* __restrict__ qk1,
    const float* __restrict__ qc1, const float* __restrict__ Wv,
    const float* __restrict__ bv, float* __restrict__ out) {
  __shared__ float msk[TT];  // 800 B broadcast table
  const int tid = threadIdx.x;
  const int lane = tid & 63;
  const int h = tid >> 6;  // wave == head
  const int b = blockIdx.x;

  for (int i = tid; i < TT; i += 512) msk[i] = mask[(size_t)b * TT + i];

  const float* kp = qk1 + ((size_t)b * NH + h) * DM;
  const float4 ka = *(const float4*)(kp + 4 * lane);
  const float4 kb = *(const float4*)(kp + 256 + 4 * lane);
  const float qc = qc1[(size_t)b * NH + h];
  __syncthreads();

  float4 cA = make_float4(0.f, 0.f, 0.f, 0.f);
  float4 cB = make_float4(0.f, 0.f, 0.f, 0.f);
  float ls = 0.f;

#define ATTN_ROW(RA, RB, MV)                        \
  {                                                 \
    const float v = wred64(dot8(RA, RB, ka, kb));   \
    const float w = __expf(v + qc + (MV));          \
    ls += w;                                        \
    cA.x = fmaf(w, RA.x, cA.x);                     \
    cA.y = fmaf(w, RA.y, cA.y);                     \
    cA.z = fmaf(w, RA.z, cA.z);                     \
    cA.w = fmaf(w, RA.w, cA.w);                     \
    cB.x = fmaf(w, RB.x, cB.x);                     \
    cB.y = fmaf(w, RB.y, cB.y);                     \
    cB.z = fmaf(w, RB.z, cB.z);                     \
    cB.w = fmaf(w, RB.w, cB.w);                     \
  }

  // stream rows 0..198 (prev), unroll 2, prefetch 2 rows ahead
  const float* pa = prev + (size_t)b * HIST * DM + 4 * lane;
  float4 r0a = *(const float4*)(pa);
  float4 r0b = *(const float4*)(pa + 256);
  float4 r1a = *(const float4*)(pa + DM);
  float4 r1b = *(const float4*)(pa + DM + 256);
  for (int i = 0; i < 198; i += 2) {
    const float* np0 = pa + (size_t)(i + 2) * DM;  // i+2 <= 198 in-loop
    int i3 = i + 3;
    if (i3 > 198) i3 = 198;
    const float* np1 = pa + (size_t)i3 * DM;
    const float4 q0a = *(const float4*)(np0);
    const float4 q0b = *(const float4*)(np0 + 256);
    const float4 q1a = *(const float4*)(np1);
    const float4 q1b = *(const float4*)(np1 + 256);
    ATTN_ROW(r0a, r0b, msk[i])
    ATTN_ROW(r1a, r1b, msk[i + 1])
    r0a = q0a;
    r0b = q0b;
    r1a = q1a;
    r1b = q1b;
  }
  ATTN_ROW(r0a, r0b, msk[198])  // row 198 (last prev)
  {                             // row 199 = current embed
    const float* cp = cur + (size_t)b * DM + 4 * lane;
    const float4 xa = *(const float4*)(cp);
    const float4 xb = *(const float4*)(cp + 256);
    ATTN_ROW(xa, xb, msk[199])
  }
#undef ATTN_ROW

  // wave-local out projection for head h; normalization deferred (linearity)
  const float linv = 1.0f / ls;
  float keep = 0.f;
  for (int r = 0; r < 64; ++r) {
    const float* wvp = Wv + (size_t)(h * 64 + r) * DM;
    const float4 wa = *(const float4*)(wvp + 4 * lane);
    const float4 wb = *(const float4*)(wvp + 256 + 4 * lane);
    float p = wred64(dot8(cA, cB, wa, wb));
    if (lane == r) keep = p;
  }
  out[(size_t)b * DM + h * 64 + lane] = keep * linv + bv[h * 64 + lane];
}

extern "C" void kernel_launch(void* const* d_in, const int* in_sizes, int n_in,
                              void* d_out, int out_size, void* d_ws,
                              size_t ws_size, hipStream_t stream) {
  const float* cur = (const float*)d_in[0];   // [1024, 512]
  const float* prev = (const float*)d_in[1];  // [1024, 199, 512]
  const float* mask = (const float*)d_in[2];  // [1024, 200]
  const float* Wq = (const float*)d_in[3];    // [512, 512]
  const float* bq = (const float*)d_in[4];    // [512]
  const float* Wk = (const float*)d_in[5];
  const float* bk = (const float*)d_in[6];
  const float* Wv = (const float*)d_in[7];
  const float* bv = (const float*)d_in[8];
  float* out = (float*)d_out;  // [1024, 512] fp32

  // workspace: q [1024*512] | qk1 [1024*8*512] | qc1 [1024*8]  (~18.9 MB)
  float* q = (float*)d_ws;
  float* qk1 = q + (size_t)BS * DM;
  float* qc1 = qk1 + (size_t)BS * NH * DM;

  qproj_kernel<<<1024, 256, 0, stream>>>(cur, Wq, bq, q);
  qk_kernel<<<1024, 256, 0, stream>>>(q, Wk, bk, qk1, qc1);
  attn_kernel<<<1024, 512, 0, stream>>>(cur, prev, mask, qk1, qc1, Wv, bv, out);
}